// Round 13
// baseline (95.217 us; speedup 1.0000x reference)
//
#include <hip/hip_runtime.h>
#include <stdint.h>

#define M_TOTAL 16384
#define N_TOTAL 1024
#define K_TOTAL 1024
#define BM 256
#define BN 128
#define BK 32
#define NTILES (K_TOTAL / BK)                 // 32
#define NWG ((M_TOTAL / BM) * (N_TOTAL / BN)) // 512

using f32x4  = __attribute__((ext_vector_type(4))) float;
using bf16x8 = __attribute__((ext_vector_type(8))) short;
using bf16x4 = __attribute__((ext_vector_type(4))) short;

#define AS1 __attribute__((address_space(1)))
#define AS3 __attribute__((address_space(3)))
#define SB() __builtin_amdgcn_sched_barrier(0)

__device__ __forceinline__ unsigned packrne(float x, float y) {
    unsigned ux = __builtin_bit_cast(unsigned, x);
    unsigned uy = __builtin_bit_cast(unsigned, y);
    ux += 0x7fffu + ((ux >> 16) & 1u);
    uy += 0x7fffu + ((uy >> 16) & 1u);
    return (ux >> 16) | (uy & 0xffff0000u);
}

// ---------------- kernel 1: W fp32 -> bf16 (4 MB read / 2 MB write) ---------
#define N8W (N_TOTAL * K_TOTAL / 8)   // 131072
__global__ __launch_bounds__(256) void cvtW_kernel(
    const float* __restrict__ W, uint4* __restrict__ Wb)
{
    const int i = blockIdx.x * 256 + threadIdx.x;
    const f32x4* p = (const f32x4*)W + (size_t)i * 2;
    const f32x4 a = p[0], b = p[1];
    uint4 r;
    r.x = packrne(a[0], a[1]);
    r.y = packrne(a[2], a[3]);
    r.z = packrne(b[0], b[1]);
    r.w = packrne(b[2], b[3]);
    Wb[i] = r;
}

// ---------------- kernel 2: fp32-X-in-LDS GEMM + bias -----------------------
// C[m][n] = sum_k X[m][k]*W[n][k] + bias[n].  X staged fp32 via gload_lds
// (no cvt pass, no loop-carried fp32 regs -> no spill path), converted to
// bf16 during LDS->reg frag read (2x ds_read_b128 + 8 packrne per frag).
// 256x128 tile, BK=32, 4 waves (2M x 2N, wave-tile 128x64 = 44 FLOP/LDS-B),
// LDS 80KB (A 2x32KB fp32, B 2x8KB bf16) -> 2 blocks/CU (r12's proven win).
// Schedule/tile: B1 -> stage(t+1) 10 gload_lds -> VM(10) counted -> B2 ->
// compute (32 MFMA, two 4-frag groups, setprio).
// Swizzles: A row r (128B, 8 slots): slot s^(r&7); B row r (64B, 4 slots):
// slot s^(r&3).  Linear gload_lds dest + pre-swizzled global source.
__global__ __launch_bounds__(256) void gemm_xf32_kernel(
    const float* __restrict__ X, const unsigned short* __restrict__ Wb,
    const float* __restrict__ bias, float* __restrict__ C)
{
    __shared__ __align__(16) char smem[81920]; // A0@0 A1@32768 B0@65536 B1@73728

    const int tid  = threadIdx.x;
    const int lane = tid & 63;
    const int wave = tid >> 6;      // 0..3
    const int wr = wave >> 1;       // 0..1 : 128-row strip
    const int wc = wave & 1;        // 0..1 : 64-col strip

    // XCD-chunked swizzle (verified r2-r12): 512 % 8 == 0
    const int bid  = blockIdx.x;
    const int work = (bid & 7) * (NWG / 8) + (bid >> 3);
    const int bm = work >> 3;
    const int bn = work & 7;
    const int m0 = bm * BM, n0 = bn * BN;

    // ---- staging (per wave per tile: A 8 ops + B 2 ops = 10 gload_lds) -----
    // A op: 1KB = 8 rows x 128B; lane l -> row l>>3, slot l&7;
    //       source k-slot (l&7)^((l>>3)&7), 4 fp32 = 16B.
    const int arow8 = lane >> 3;
    const int aslot = ((lane & 7) ^ ((lane >> 3) & 7)) * 4;   // fp32 elems
    // B op: 1KB = 16 rows x 64B; lane l -> row l>>2, slot l&3;
    //       source k-slot (l&3)^((l>>2)&3), 8 bf16 = 16B.
    const int brow16 = lane >> 2;
    const int bslot  = ((lane & 3) ^ ((lane >> 2) & 3)) * 8;  // bf16 elems

    auto stage = [&](int t, int b) {
        #pragma unroll
        for (int j = 0; j < 8; ++j) {           // A: 8 x 32-row... (8 ops x 8 rows, wave-strided)
            const int rb = j * 32 + wave * 8;   // row base of this 1KB op
            __builtin_amdgcn_global_load_lds(
                (const AS1 void*)(X + (size_t)(m0 + rb + arow8) * K_TOTAL
                                     + t * BK + aslot),
                (AS3 void*)(smem + b * 32768 + rb * 128), 16, 0, 0);
        }
        #pragma unroll
        for (int j = 0; j < 2; ++j) {           // B: 2 ops x 16 rows
            const int rb = j * 64 + wave * 16;
            __builtin_amdgcn_global_load_lds(
                (const AS1 void*)(Wb + (size_t)(n0 + rb + brow16) * K_TOTAL
                                     + t * BK + bslot),
                (AS3 void*)(smem + 65536 + b * 8192 + rb * 64), 16, 0, 0);
        }
    };

    const int cl = lane & 15;
    const int kb = lane >> 4;       // 0..3: k-group (8 elems) within BK=32

    f32x4 acc[8][4] = {};

#define BARRIER() SB(); __builtin_amdgcn_s_barrier(); SB()
#define VM(N)     asm volatile("s_waitcnt vmcnt(" #N ")" ::: "memory"); SB()

    // A-frag i: row = wr*128 + i*16 + cl; fp32 k 8*kb..+8 = 32B = slots
    // {2kb, 2kb+1} ^ (row&7).  Read 2 x f32x4, pack to bf16x8.
    auto read_a = [&](const char* Ab, int i) -> bf16x8 {
        const int row = wr * 128 + i * 16 + cl;
        const int rs  = row & 7;
        const f32x4 v0 = *(const f32x4*)(Ab + row * 128 + (((2 * kb)     ^ rs) << 4));
        const f32x4 v1 = *(const f32x4*)(Ab + row * 128 + (((2 * kb + 1) ^ rs) << 4));
        uint4 c;
        c.x = packrne(v0[0], v0[1]);
        c.y = packrne(v0[2], v0[3]);
        c.z = packrne(v1[0], v1[1]);
        c.w = packrne(v1[2], v1[3]);
        return __builtin_bit_cast(bf16x8, c);
    };
    auto read_b = [&](const char* Bb, int j) -> bf16x8 {
        const int row = wc * 64 + j * 16 + cl;
        return *(const bf16x8*)(Bb + row * 64 + ((kb ^ (row & 3)) << 4));
    };

    auto compute_tile = [&](int buf) {
        const char* Ab = smem + buf * 32768;
        const char* Bb = smem + 65536 + buf * 8192;
        bf16x8 bF[4], aF[4];
        #pragma unroll
        for (int j = 0; j < 4; ++j) bF[j] = read_b(Bb, j);
        // group 1: A-frags 0-3 (acc rows 0-3)
        #pragma unroll
        for (int i = 0; i < 4; ++i) aF[i] = read_a(Ab, i);
        __builtin_amdgcn_s_setprio(1);
        #pragma unroll
        for (int i = 0; i < 4; ++i)
            #pragma unroll
            for (int j = 0; j < 4; ++j)
                acc[i][j] = __builtin_amdgcn_mfma_f32_16x16x32_bf16(
                    aF[i], bF[j], acc[i][j], 0, 0, 0);
        __builtin_amdgcn_s_setprio(0);
        // group 2: A-frags 4-7 (acc rows 4-7)
        #pragma unroll
        for (int i = 0; i < 4; ++i) aF[i] = read_a(Ab, 4 + i);
        __builtin_amdgcn_s_setprio(1);
        #pragma unroll
        for (int i = 0; i < 4; ++i)
            #pragma unroll
            for (int j = 0; j < 4; ++j)
                acc[4 + i][j] = __builtin_amdgcn_mfma_f32_16x16x32_bf16(
                    aF[i], bF[j], acc[4 + i][j], 0, 0, 0);
        __builtin_amdgcn_s_setprio(0);
    };

    // ---- prologue: tiles 0,1 staged; tile 0 landed, tile 1 in flight -------
    stage(0, 0);
    stage(1, 1);
    VM(10);
    BARRIER();
    compute_tile(0);

    // ---- main loop ---------------------------------------------------------
    #pragma unroll 1
    for (int t = 1; t < NTILES; ++t) {
        const int buf = t & 1;
        BARRIER();                          // B1: all waves done reading buf^1's old tile
        if (t + 1 < NTILES) {
            stage(t + 1, buf ^ 1);
            VM(10);                         // retire tile-t's 10; t+1's stay in flight
        } else {
            VM(0);                          // final tile: drain
        }
        BARRIER();                          // B2: tile t fully in LDS
        compute_tile(buf);
    }

    // ---- epilogue: D element (row=(lane>>4)*4+r, col=lane&15) [m89] --------
    const int r0 = (lane >> 4) * 4;
    #pragma unroll
    for (int ni = 0; ni < 4; ++ni) {
        const int n = n0 + wc * 64 + ni * 16 + cl;
        const float bvv = bias[n];
        #pragma unroll
        for (int mi = 0; mi < 8; ++mi) {
            const int m = m0 + wr * 128 + mi * 16 + r0;
            #pragma unroll
            for (int r = 0; r < 4; ++r)
                C[(size_t)(m + r) * N_TOTAL + n] = acc[mi][ni][r] + bvv;
        }
    }
#undef BARRIER
#undef VM
}

// ---------------- fallback: round-1 single kernel (known-good) --------------
__device__ __forceinline__ short f2bf(float f) {
    unsigned u = __builtin_bit_cast(unsigned, f);
    u += 0x7fffu + ((u >> 16) & 1u);
    return (short)(u >> 16);
}

#define FBM 128
#define FBN 128
#define FBK 64
#define FNWG ((M_TOTAL / FBM) * (N_TOTAL / FBN))   // 1024

__global__ __launch_bounds__(256) void fb_gemm_bias_kernel(
    const float* __restrict__ X, const float* __restrict__ W,
    const float* __restrict__ bias, float* __restrict__ C)
{
    __shared__ short As[FBM * FBK];
    __shared__ short Bs[FBN * FBK];

    const int tid  = threadIdx.x;
    const int lane = tid & 63;
    const int wave = tid >> 6;
    const int wr = wave >> 1;
    const int wc = wave & 1;

    const int bid  = blockIdx.x;
    const int work = (bid & 7) * (FNWG / 8) + (bid >> 3);
    const int bm = work >> 3;
    const int bn = work & 7;
    const int m0 = bm * FBM, n0 = bn * FBN;

    const int srow  = tid >> 4;
    const int scol4 = tid & 15;

    f32x4 acc[4][4] = {};
    char* const Ab = (char*)As;
    char* const Bb = (char*)Bs;

    for (int k0 = 0; k0 < K_TOTAL; k0 += FBK) {
        __syncthreads();
        #pragma unroll
        for (int pass = 0; pass < 8; ++pass) {
            const int row = srow + pass * 16;
            const int off = (row * (FBK * 2) + scol4 * 8) ^ ((row & 7) << 4);
            {
                const f32x4 v = *(const f32x4*)(X + (size_t)(m0 + row) * K_TOTAL + k0 + scol4 * 4);
                bf16x4 b;
                b[0] = f2bf(v[0]); b[1] = f2bf(v[1]); b[2] = f2bf(v[2]); b[3] = f2bf(v[3]);
                *(bf16x4*)(Ab + off) = b;
            }
            {
                const f32x4 v = *(const f32x4*)(W + (size_t)(n0 + row) * K_TOTAL + k0 + scol4 * 4);
                bf16x4 b;
                b[0] = f2bf(v[0]); b[1] = f2bf(v[1]); b[2] = f2bf(v[2]); b[3] = f2bf(v[3]);
                *(bf16x4*)(Bb + off) = b;
            }
        }
        __syncthreads();

        #pragma unroll
        for (int ks = 0; ks < 2; ++ks) {
            const int kel = ks * 32 + ((lane >> 4) << 3);
            bf16x8 af[4], bfr[4];
            #pragma unroll
            for (int i = 0; i < 4; ++i) {
                const int ar = wr * 64 + i * 16 + (lane & 15);
                af[i]  = *(const bf16x8*)(Ab + ((ar * (FBK * 2) + kel * 2) ^ ((ar & 7) << 4)));
                const int br = wc * 64 + i * 16 + (lane & 15);
                bfr[i] = *(const bf16x8*)(Bb + ((br * (FBK * 2) + kel * 2) ^ ((br & 7) << 4)));
            }
            #pragma unroll
            for (int mi = 0; mi < 4; ++mi)
                #pragma unroll
                for (int ni = 0; ni < 4; ++ni)
                    acc[mi][ni] = __builtin_amdgcn_mfma_f32_16x16x32_bf16(
                        af[mi], bfr[ni], acc[mi][ni], 0, 0, 0);
        }
    }

    const int cl = lane & 15;
    const int r0 = (lane >> 4) * 4;
    #pragma unroll
    for (int ni = 0; ni < 4; ++ni) {
        const int n = n0 + wc * 64 + ni * 16 + cl;
        const float bvv = bias[n];
        #pragma unroll
        for (int mi = 0; mi < 4; ++mi) {
            const int m = m0 + wr * 64 + mi * 16 + r0;
            #pragma unroll
            for (int r = 0; r < 4; ++r)
                C[(size_t)(m + r) * N_TOTAL + n] = acc[mi][ni][r] + bvv;
        }
    }
}

extern "C" void kernel_launch(void* const* d_in, const int* in_sizes, int n_in,
                              void* d_out, int out_size, void* d_ws, size_t ws_size,
                              hipStream_t stream) {
    // inputs: 0:X 1:Wq 2:bq 3:Wk 4:bk 5:Wv 6:bv
    // softmax rows sum to 1 => out = X @ Wv^T + bv exactly.
    const float* X  = (const float*)d_in[0];
    const float* Wv = (const float*)d_in[5];
    const float* bv = (const float*)d_in[6];
    float* out = (float*)d_out;

    const size_t WB_BYTES = (size_t)N_TOTAL * K_TOTAL * 2;   // 2 MiB

    if (ws_size >= WB_BYTES) {
        unsigned short* Wb = (unsigned short*)d_ws;
        cvtW_kernel<<<dim3(N8W / 256), dim3(256), 0, stream>>>(Wv, (uint4*)Wb);
        gemm_xf32_kernel<<<dim3(NWG), dim3(256), 0, stream>>>(X, Wb, bv, out);
    } else {
        fb_gemm_bias_kernel<<<dim3(FNWG), dim3(256), 0, stream>>>(X, Wv, bv, out);
    }
}

// Round 14
// 62.804 us; speedup vs baseline: 1.5161x; 1.5161x over previous
//
#include <hip/hip_runtime.h>
#include <stdint.h>

#define M_TOTAL 16384
#define N_TOTAL 1024
#define K_TOTAL 1024
#define BM 128
#define BN 128
#define BK 64
#define NTILES (K_TOTAL / BK)                 // 16
#define NWG ((M_TOTAL / BM) * (N_TOTAL / BN)) // 1024

using f32x4  = __attribute__((ext_vector_type(4))) float;
using bf16x8 = __attribute__((ext_vector_type(8))) short;
using bf16x4 = __attribute__((ext_vector_type(4))) short;

#define AS1 __attribute__((address_space(1)))
#define AS3 __attribute__((address_space(3)))
#define SB() __builtin_amdgcn_sched_barrier(0)

__device__ __forceinline__ unsigned packrne(float x, float y) {
    unsigned ux = __builtin_bit_cast(unsigned, x);
    unsigned uy = __builtin_bit_cast(unsigned, y);
    ux += 0x7fffu + ((ux >> 16) & 1u);
    uy += 0x7fffu + ((uy >> 16) & 1u);
    return (ux >> 16) | (uy & 0xffff0000u);
}

// ---------------- kernel 1: X -> bf16 row-major; W -> bf16 FRAG-ORDER -------
// Wf chunk (J, h, l): content = W[J*16 + (l&15)][h*32 + (l>>4)*8 .. +8]
// (r5-verified layout).  A GEMM wave loads a B-fragment as one contiguous
// 1KB dwordx4 burst: chunk idx = J*2048 + h*64 + lane.
#define N8X (M_TOTAL * K_TOTAL / 8)   // 2097152
#define NWF (N_TOTAL * K_TOTAL / 8)   // 131072
__global__ __launch_bounds__(256) void cvt2_kernel(
    const float* __restrict__ X, const float* __restrict__ W,
    uint4* __restrict__ Xb, uint4* __restrict__ Wf)
{
    const int i = blockIdx.x * 256 + threadIdx.x;
    if (i < N8X) {
        const f32x4* p = (const f32x4*)X + (size_t)i * 2;
        const f32x4 a = p[0], b = p[1];
        uint4 r;
        r.x = packrne(a[0], a[1]);
        r.y = packrne(a[2], a[3]);
        r.z = packrne(b[0], b[1]);
        r.w = packrne(b[2], b[3]);
        Xb[i] = r;
    } else {
        const int idx = i - N8X;          // [0, NWF)
        const int J   = idx >> 11;        // 64 J-groups, 2048 chunks each
        const int rem = idx & 2047;
        const int h   = rem >> 6;         // 0..31 (32-k half)
        const int l   = rem & 63;
        const int cl = l & 15, kb = l >> 4;
        const float* src = W + (size_t)(J * 16 + cl) * K_TOTAL + h * 32 + kb * 8;
        const f32x4 a = *(const f32x4*)src;
        const f32x4 b = *(const f32x4*)(src + 4);
        uint4 r;
        r.x = packrne(a[0], a[1]);
        r.y = packrne(a[2], a[3]);
        r.z = packrne(b[0], b[1]);
        r.w = packrne(b[2], b[3]);
        Wf[idx] = r;
    }
}

// ---------------- kernel 2: r12 skeleton, B direct-to-registers -------------
// C[m][n] = sum_k Xb[m][k]*W[n][k] + bias[n].  128x128 tile, 4 waves (2x2,
// wave-tile 64x64), BK=64.  LDS = A ONLY, 2x16KB dbuf (32KB) -> 3+ blocks/CU
// target.  B frags loaded straight from L2-resident Wf (1KB/wave coalesced),
// double-buffered in regs (static ping-pong).  Per tile: B1 barrier ->
// stage_A(t+1) 4 gload_lds + load_B(t+1) 8 reg-loads -> VM(12) counted
// (retires A(t)+B(t), 1 tile old; t+1's 12 stay in flight) -> B2 barrier ->
// compute (2 k-halves x 16 MFMA, setprio).
// A LDS: row r (128B, 8 slots), slot s holds kg = s^(r&7); linear gload_lds
// dest + pre-swizzled source (r12-proven, 0 conflicts).
__global__ __launch_bounds__(256) void gemm_bd_kernel(
    const unsigned short* __restrict__ Xb, const unsigned short* __restrict__ Wfu,
    const float* __restrict__ bias, float* __restrict__ C)
{
    __shared__ __align__(16) char smem[32768];  // A0 @0, A1 @16384

    const int tid  = threadIdx.x;
    const int lane = tid & 63;
    const int wave = tid >> 6;      // 0..3
    const int wr = wave >> 1;       // 0..1 : 64-row strip
    const int wc = wave & 1;        // 0..1 : 64-col strip

    // XCD-chunked swizzle (verified r2-r13)
    const int bid  = blockIdx.x;
    const int work = (bid & 7) * (NWG / 8) + (bid >> 3);
    const int bm = work >> 3;
    const int bn = work & 7;
    const int m0 = bm * BM, n0 = bn * BN;

    // ---- A staging: gload_lds, linear dest + pre-swizzled source (r12) -----
    const int srow = wave * 8 + (lane >> 3);
    const int kge  = ((lane & 7) ^ ((lane >> 3) & 7)) * 8;
    auto stage_A = [&](int t, int b) {
        #pragma unroll
        for (int j = 0; j < 4; ++j) {
            __builtin_amdgcn_global_load_lds(
                (const AS1 void*)(Xb + (size_t)(m0 + j * 32 + srow) * K_TOTAL
                                     + t * BK + kge),
                (AS3 void*)(smem + b * 16384 + j * 4096 + wave * 1024),
                16, 0, 0);
        }
    };

    // ---- B direct loads: frag (jj, kh) of tile t at Wf chunk
    //      (Jbase+jj)*2048 + (t*2+kh)*64 + lane  -- 1KB/wave contiguous.
    const uint4* Wf = (const uint4*)Wfu;
    const int Jbase = (n0 + wc * 64) >> 4;
    auto load_B = [&](int t, bf16x8 (&B)[4][2]) {
        #pragma unroll
        for (int jj = 0; jj < 4; ++jj)
            #pragma unroll
            for (int kh = 0; kh < 2; ++kh)
                B[jj][kh] = __builtin_bit_cast(bf16x8,
                    Wf[(size_t)(Jbase + jj) * 2048 + (t * 2 + kh) * 64 + lane]);
    };

    const int cl = lane & 15;
    const int kb = lane >> 4;       // 0..3

    f32x4 acc[4][4] = {};

#define BARRIER() SB(); __builtin_amdgcn_s_barrier(); SB()
#define VM(N)     asm volatile("s_waitcnt vmcnt(" #N ")" ::: "memory"); SB()

    auto compute_tile = [&](int buf, bf16x8 (&Bc)[4][2]) {
        const char* Ab = smem + buf * 16384;
        #pragma unroll
        for (int kh = 0; kh < 2; ++kh) {
            const int kg = kh * 4 + kb;
            bf16x8 aF[4];
            #pragma unroll
            for (int i = 0; i < 4; ++i) {
                const int ar = wr * 64 + i * 16 + cl;
                aF[i] = *(const bf16x8*)(Ab + ar * 128 + ((kg ^ (ar & 7)) << 4));
            }
            __builtin_amdgcn_s_setprio(1);
            #pragma unroll
            for (int i = 0; i < 4; ++i)
                #pragma unroll
                for (int jj = 0; jj < 4; ++jj)
                    acc[i][jj] = __builtin_amdgcn_mfma_f32_16x16x32_bf16(
                        aF[i], Bc[jj][kh], acc[i][jj], 0, 0, 0);
            __builtin_amdgcn_s_setprio(0);
        }
    };

    // static reg ping-pong for B (rule #20)
    bf16x8 B0r[4][2], B1r[4][2];

    // one iteration: consume tile T (buf = T&1, Bcur); prefetch T+1 into Bnxt
#define ITER(T, BCUR, BNXT)                                                     \
    {                                                                           \
        BARRIER();                      /* B1: reads of nbuf's old tile done */ \
        if ((T) + 1 < NTILES) {                                                 \
            stage_A((T) + 1, ((T) & 1) ^ 1);                                    \
            load_B((T) + 1, BNXT);                                              \
            VM(12);                     /* retire A(T)+B(T); T+1's 12 fly */    \
        } else {                                                                \
            VM(0);                      /* final tile: drain */                 \
        }                                                                       \
        BARRIER();                      /* B2: tile T fully in LDS */           \
        compute_tile((T) & 1, BCUR);                                            \
    }

    // ---- prologue: tiles 0,1 in flight; tile 0 retired -> compute ----------
    stage_A(0, 0);
    load_B(0, B0r);
    stage_A(1, 1);
    load_B(1, B1r);
    VM(12);          // retire A(0)+B(0); A(1)+B(1) stay in flight
    BARRIER();
    compute_tile(0, B0r);

    // ---- main loop: tiles 1..14 in pairs, tile 15 peeled -------------------
    #pragma unroll 1
    for (int t = 1; t < NTILES - 1; t += 2) {
        ITER(t,     B1r, B0r);      // consume B(t)=B1r, prefetch into B0r
        ITER(t + 1, B0r, B1r);      // consume B(t+1)=B0r, prefetch into B1r
    }
    ITER(NTILES - 1, B1r, B0r);     // t=15 (odd -> B1r); takes VM(0) branch

    // ---- epilogue: D element (row=(lane>>4)*4+r, col=lane&15) [m89] --------
    const int r0 = (lane >> 4) * 4;
    #pragma unroll
    for (int ni = 0; ni < 4; ++ni) {
        const int n = n0 + wc * 64 + ni * 16 + cl;
        const float bvv = bias[n];
        #pragma unroll
        for (int mi = 0; mi < 4; ++mi) {
            const int m = m0 + wr * 64 + mi * 16 + r0;
            #pragma unroll
            for (int r = 0; r < 4; ++r)
                C[(size_t)(m + r) * N_TOTAL + n] = acc[mi][ni][r] + bvv;
        }
    }
#undef ITER
#undef BARRIER
#undef VM
}

// ---------------- fallback: round-1 single kernel (known-good) --------------
__device__ __forceinline__ short f2bf(float f) {
    unsigned u = __builtin_bit_cast(unsigned, f);
    u += 0x7fffu + ((u >> 16) & 1u);
    return (short)(u >> 16);
}

__global__ __launch_bounds__(256) void fb_gemm_bias_kernel(
    const float* __restrict__ X, const float* __restrict__ W,
    const float* __restrict__ bias, float* __restrict__ C)
{
    __shared__ short As[BM * BK];
    __shared__ short Bs[BN * BK];

    const int tid  = threadIdx.x;
    const int lane = tid & 63;
    const int wave = tid >> 6;
    const int wr = wave >> 1;
    const int wc = wave & 1;

    const int bid  = blockIdx.x;
    const int work = (bid & 7) * (NWG / 8) + (bid >> 3);
    const int bm = work >> 3;
    const int bn = work & 7;
    const int m0 = bm * BM, n0 = bn * BN;

    const int srow  = tid >> 4;
    const int scol4 = tid & 15;

    f32x4 acc[4][4] = {};
    char* const Ab = (char*)As;
    char* const Bb = (char*)Bs;

    for (int k0 = 0; k0 < K_TOTAL; k0 += BK) {
        __syncthreads();
        #pragma unroll
        for (int pass = 0; pass < 8; ++pass) {
            const int row = srow + pass * 16;
            const int off = (row * (BK * 2) + scol4 * 8) ^ ((row & 7) << 4);
            {
                const f32x4 v = *(const f32x4*)(X + (size_t)(m0 + row) * K_TOTAL + k0 + scol4 * 4);
                bf16x4 b;
                b[0] = f2bf(v[0]); b[1] = f2bf(v[1]); b[2] = f2bf(v[2]); b[3] = f2bf(v[3]);
                *(bf16x4*)(Ab + off) = b;
            }
            {
                const f32x4 v = *(const f32x4*)(W + (size_t)(n0 + row) * K_TOTAL + k0 + scol4 * 4);
                bf16x4 b;
                b[0] = f2bf(v[0]); b[1] = f2bf(v[1]); b[2] = f2bf(v[2]); b[3] = f2bf(v[3]);
                *(bf16x4*)(Bb + off) = b;
            }
        }
        __syncthreads();

        #pragma unroll
        for (int ks = 0; ks < 2; ++ks) {
            const int kel = ks * 32 + ((lane >> 4) << 3);
            bf16x8 af[4], bfr[4];
            #pragma unroll
            for (int i = 0; i < 4; ++i) {
                const int ar = wr * 64 + i * 16 + (lane & 15);
                af[i]  = *(const bf16x8*)(Ab + ((ar * (BK * 2) + kel * 2) ^ ((ar & 7) << 4)));
                const int br = wc * 64 + i * 16 + (lane & 15);
                bfr[i] = *(const bf16x8*)(Bb + ((br * (BK * 2) + kel * 2) ^ ((br & 7) << 4)));
            }
            #pragma unroll
            for (int mi = 0; mi < 4; ++mi)
                #pragma unroll
                for (int ni = 0; ni < 4; ++ni)
                    acc[mi][ni] = __builtin_amdgcn_mfma_f32_16x16x32_bf16(
                        af[mi], bfr[ni], acc[mi][ni], 0, 0, 0);
        }
    }

    const int cl = lane & 15;
    const int r0 = (lane >> 4) * 4;
    #pragma unroll
    for (int ni = 0; ni < 4; ++ni) {
        const int n = n0 + wc * 64 + ni * 16 + cl;
        const float bvv = bias[n];
        #pragma unroll
        for (int mi = 0; mi < 4; ++mi) {
            const int m = m0 + wr * 64 + mi * 16 + r0;
            #pragma unroll
            for (int r = 0; r < 4; ++r)
                C[(size_t)(m + r) * N_TOTAL + n] = acc[mi][ni][r] + bvv;
        }
    }
}

extern "C" void kernel_launch(void* const* d_in, const int* in_sizes, int n_in,
                              void* d_out, int out_size, void* d_ws, size_t ws_size,
                              hipStream_t stream) {
    // inputs: 0:X 1:Wq 2:bq 3:Wk 4:bk 5:Wv 6:bv
    // softmax rows sum to 1 => out = X @ Wv^T + bv exactly.
    const float* X  = (const float*)d_in[0];
    const float* Wv = (const float*)d_in[5];
    const float* bv = (const float*)d_in[6];
    float* out = (float*)d_out;

    const size_t XB_BYTES = (size_t)M_TOTAL * K_TOTAL * 2;   // 32 MiB
    const size_t WF_BYTES = (size_t)N_TOTAL * K_TOTAL * 2;   // 2 MiB

    if (ws_size >= XB_BYTES + WF_BYTES) {
        unsigned short* Xb = (unsigned short*)d_ws;
        unsigned short* Wf = (unsigned short*)((char*)d_ws + XB_BYTES);
        cvt2_kernel<<<dim3((N8X + NWF) / 256), dim3(256), 0, stream>>>(
            X, Wv, (uint4*)Xb, (uint4*)Wf);
        gemm_bd_kernel<<<dim3(NWG), dim3(256), 0, stream>>>(Xb, Wf, bv, out);
    } else {
        fb_gemm_bias_kernel<<<dim3(NWG), dim3(256), 0, stream>>>(X, Wv, bv, out);
    }
}

// Round 15
// 61.118 us; speedup vs baseline: 1.5579x; 1.0276x over previous
//
#include <hip/hip_runtime.h>
#include <stdint.h>

#define M_TOTAL 16384
#define N_TOTAL 1024
#define K_TOTAL 1024
#define BM 128
#define BN 128
#define BK 64
#define NTILES (K_TOTAL / BK)                 // 16
#define NWG ((M_TOTAL / BM) * (N_TOTAL / BN)) // 1024

using f32x4  = __attribute__((ext_vector_type(4))) float;
using bf16x8 = __attribute__((ext_vector_type(8))) short;
using bf16x4 = __attribute__((ext_vector_type(4))) short;

#define AS1 __attribute__((address_space(1)))
#define AS3 __attribute__((address_space(3)))
#define SB() __builtin_amdgcn_sched_barrier(0)

__device__ __forceinline__ unsigned packrne(float x, float y) {
    unsigned ux = __builtin_bit_cast(unsigned, x);
    unsigned uy = __builtin_bit_cast(unsigned, y);
    ux += 0x7fffu + ((ux >> 16) & 1u);
    uy += 0x7fffu + ((uy >> 16) & 1u);
    return (ux >> 16) | (uy & 0xffff0000u);
}

// ---------------- kernel 1: fused fp32->bf16 convert of X and Wv ------------
#define N8X (M_TOTAL * K_TOTAL / 8)   // 2097152
#define N8W (N_TOTAL * K_TOTAL / 8)   // 131072
__global__ __launch_bounds__(256) void cvt2_kernel(
    const float* __restrict__ X, const float* __restrict__ W,
    uint4* __restrict__ Xb, uint4* __restrict__ Wb)
{
    const int i = blockIdx.x * 256 + threadIdx.x;
    const float* src; uint4* dst; int idx;
    if (i < N8X) { src = X; dst = Xb; idx = i; }
    else         { src = W; dst = Wb; idx = i - N8X; }
    const f32x4* p = (const f32x4*)src + (size_t)idx * 2;
    const f32x4 a = p[0], b = p[1];
    uint4 r;
    r.x = packrne(a[0], a[1]);
    r.y = packrne(a[2], a[3]);
    r.z = packrne(b[0], b[1]);
    r.w = packrne(b[2], b[3]);
    dst[idx] = r;
}

// ---------------- kernel 2: r12 skeleton, 8 waves per 128^2 block -----------
// C[m][n] = sum_k Xb[m][k]*Wb[n][k] + bias[n].  bf16 inputs from ws.
// 512 thr = 8 waves (4M x 2N, wave-tile 32x64), BK=64, LDS 64KB dbuf ->
// 2 blocks/CU AND 4 waves/SIMD (single change vs r12: 2x TLP to cover the
// per-tile vmcnt/barrier skew that r12-r14 counters show as ~55% idle).
// Per tile: B1 barrier -> stage(t+1) 4 gload_lds -> VM(4) counted -> B2
// barrier -> compute (2 k-halves x 8 MFMA, setprio).
// LDS: row r (128B, 8 slots), slot s holds kg = s^(r&7); linear gload_lds
// dest + pre-swizzled global source (r12-proven, 0 conflicts).
__global__ __launch_bounds__(512) void gemm8w_kernel(
    const unsigned short* __restrict__ Xb, const unsigned short* __restrict__ Wb,
    const float* __restrict__ bias, float* __restrict__ C)
{
    __shared__ __align__(16) char smem[65536]; // A0@0 A1@16384 B0@32768 B1@49152

    const int tid  = threadIdx.x;
    const int lane = tid & 63;
    const int wave = tid >> 6;      // 0..7
    const int wr = wave >> 1;       // 0..3 : 32-row strip
    const int wc = wave & 1;        // 0..1 : 64-col strip

    // XCD-chunked swizzle (verified r2-r14)
    const int bid  = blockIdx.x;
    const int work = (bid & 7) * (NWG / 8) + (bid >> 3);
    const int bm = work >> 3;
    const int bn = work & 7;
    const int m0 = bm * BM, n0 = bn * BN;

    // staging: each wave owns 16 rows of A and 16 of B per tile (2 ops each).
    // Op = 1KB = 8 rows x 128B; lane l -> row +(l>>3), slot l&7; source
    // k-group (l&7)^((l>>3)&7) (pre-swizzle for linear dest).
    const int srow = lane >> 3;
    const int kge  = ((lane & 7) ^ ((lane >> 3) & 7)) * 8;

    auto stage = [&](int t, int b) {
        #pragma unroll
        for (int j = 0; j < 2; ++j) {   // A rows wave*16+j*8 .. +8
            const int rb = wave * 16 + j * 8;
            __builtin_amdgcn_global_load_lds(
                (const AS1 void*)(Xb + (size_t)(m0 + rb + srow) * K_TOTAL
                                     + t * BK + kge),
                (AS3 void*)(smem + b * 16384 + rb * 128), 16, 0, 0);
        }
        #pragma unroll
        for (int j = 0; j < 2; ++j) {   // B rows (cols) wave*16+j*8 .. +8
            const int rb = wave * 16 + j * 8;
            __builtin_amdgcn_global_load_lds(
                (const AS1 void*)(Wb + (size_t)(n0 + rb + srow) * K_TOTAL
                                     + t * BK + kge),
                (AS3 void*)(smem + 32768 + b * 16384 + rb * 128), 16, 0, 0);
        }
    };

    const int cl = lane & 15;
    const int kb = lane >> 4;       // 0..3

    f32x4 acc[2][4] = {};

#define BARRIER() SB(); __builtin_amdgcn_s_barrier(); SB()
#define VM(N)     asm volatile("s_waitcnt vmcnt(" #N ")" ::: "memory"); SB()

    auto compute_tile = [&](int buf) {
        const char* Ab = smem + buf * 16384;
        const char* Bb = smem + 32768 + buf * 16384;
        #pragma unroll
        for (int ks = 0; ks < 2; ++ks) {
            const int kg = ks * 4 + kb;
            bf16x8 aF[2], bF[4];
            #pragma unroll
            for (int i = 0; i < 2; ++i) {
                const int ar = wr * 32 + i * 16 + cl;
                aF[i] = *(const bf16x8*)(Ab + ar * 128 + ((kg ^ (ar & 7)) << 4));
            }
            #pragma unroll
            for (int j = 0; j < 4; ++j) {
                const int br = wc * 64 + j * 16 + cl;
                bF[j] = *(const bf16x8*)(Bb + br * 128 + ((kg ^ (br & 7)) << 4));
            }
            __builtin_amdgcn_s_setprio(1);
            #pragma unroll
            for (int i = 0; i < 2; ++i)
                #pragma unroll
                for (int j = 0; j < 4; ++j)
                    acc[i][j] = __builtin_amdgcn_mfma_f32_16x16x32_bf16(
                        aF[i], bF[j], acc[i][j], 0, 0, 0);
            __builtin_amdgcn_s_setprio(0);
        }
    };

    // ---- prologue: tiles 0,1 staged; tile 0 landed, tile 1 in flight -------
    stage(0, 0);
    stage(1, 1);
    VM(4);
    BARRIER();
    compute_tile(0);

    // ---- main loop ---------------------------------------------------------
    #pragma unroll 1
    for (int t = 1; t < NTILES; ++t) {
        const int buf = t & 1;
        BARRIER();                          // B1: all waves done reading buf^1's old tile
        if (t + 1 < NTILES) {
            stage(t + 1, buf ^ 1);
            VM(4);                          // retire tile-t's 4; t+1's stay in flight
        } else {
            VM(0);                          // final tile: drain
        }
        BARRIER();                          // B2: tile t fully in LDS
        compute_tile(buf);
    }

    // ---- epilogue: D element (row=(lane>>4)*4+r, col=lane&15) [m89] --------
    const int r0 = (lane >> 4) * 4;
    #pragma unroll
    for (int ni = 0; ni < 4; ++ni) {
        const int n = n0 + wc * 64 + ni * 16 + cl;
        const float bvv = bias[n];
        #pragma unroll
        for (int mi = 0; mi < 2; ++mi) {
            const int m = m0 + wr * 32 + mi * 16 + r0;
            #pragma unroll
            for (int r = 0; r < 4; ++r)
                C[(size_t)(m + r) * N_TOTAL + n] = acc[mi][ni][r] + bvv;
        }
    }
#undef BARRIER
#undef VM
}

// ---------------- fallback: round-1 single kernel (known-good) --------------
__device__ __forceinline__ short f2bf(float f) {
    unsigned u = __builtin_bit_cast(unsigned, f);
    u += 0x7fffu + ((u >> 16) & 1u);
    return (short)(u >> 16);
}

__global__ __launch_bounds__(256) void fb_gemm_bias_kernel(
    const float* __restrict__ X, const float* __restrict__ W,
    const float* __restrict__ bias, float* __restrict__ C)
{
    __shared__ short As[BM * BK];
    __shared__ short Bs[BN * BK];

    const int tid  = threadIdx.x;
    const int lane = tid & 63;
    const int wave = tid >> 6;
    const int wr = wave >> 1;
    const int wc = wave & 1;

    const int bid  = blockIdx.x;
    const int work = (bid & 7) * (NWG / 8) + (bid >> 3);
    const int bm = work >> 3;
    const int bn = work & 7;
    const int m0 = bm * BM, n0 = bn * BN;

    const int srow  = tid >> 4;
    const int scol4 = tid & 15;

    f32x4 acc[4][4] = {};
    char* const Ab = (char*)As;
    char* const Bb = (char*)Bs;

    for (int k0 = 0; k0 < K_TOTAL; k0 += BK) {
        __syncthreads();
        #pragma unroll
        for (int pass = 0; pass < 8; ++pass) {
            const int row = srow + pass * 16;
            const int off = (row * (BK * 2) + scol4 * 8) ^ ((row & 7) << 4);
            {
                const f32x4 v = *(const f32x4*)(X + (size_t)(m0 + row) * K_TOTAL + k0 + scol4 * 4);
                bf16x4 b;
                b[0] = f2bf(v[0]); b[1] = f2bf(v[1]); b[2] = f2bf(v[2]); b[3] = f2bf(v[3]);
                *(bf16x4*)(Ab + off) = b;
            }
            {
                const f32x4 v = *(const f32x4*)(W + (size_t)(n0 + row) * K_TOTAL + k0 + scol4 * 4);
                bf16x4 b;
                b[0] = f2bf(v[0]); b[1] = f2bf(v[1]); b[2] = f2bf(v[2]); b[3] = f2bf(v[3]);
                *(bf16x4*)(Bb + off) = b;
            }
        }
        __syncthreads();

        #pragma unroll
        for (int ks = 0; ks < 2; ++ks) {
            const int kel = ks * 32 + ((lane >> 4) << 3);
            bf16x8 af[4], bfr[4];
            #pragma unroll
            for (int i = 0; i < 4; ++i) {
                const int ar = wr * 64 + i * 16 + (lane & 15);
                af[i]  = *(const bf16x8*)(Ab + ((ar * (BK * 2) + kel * 2) ^ ((ar & 7) << 4)));
                const int br = wc * 64 + i * 16 + (lane & 15);
                bfr[i] = *(const bf16x8*)(Bb + ((br * (BK * 2) + kel * 2) ^ ((br & 7) << 4)));
            }
            #pragma unroll
            for (int mi = 0; mi < 4; ++mi)
                #pragma unroll
                for (int ni = 0; ni < 4; ++ni)
                    acc[mi][ni] = __builtin_amdgcn_mfma_f32_16x16x32_bf16(
                        af[mi], bfr[ni], acc[mi][ni], 0, 0, 0);
        }
    }

    const int cl = lane & 15;
    const int r0 = (lane >> 4) * 4;
    #pragma unroll
    for (int ni = 0; ni < 4; ++ni) {
        const int n = n0 + wc * 64 + ni * 16 + cl;
        const float bvv = bias[n];
        #pragma unroll
        for (int mi = 0; mi < 4; ++mi) {
            const int m = m0 + wr * 64 + mi * 16 + r0;
            #pragma unroll
            for (int r = 0; r < 4; ++r)
                C[(size_t)(m + r) * N_TOTAL + n] = acc[mi][ni][r] + bvv;
        }
    }
}

extern "C" void kernel_launch(void* const* d_in, const int* in_sizes, int n_in,
                              void* d_out, int out_size, void* d_ws, size_t ws_size,
                              hipStream_t stream) {
    // inputs: 0:X 1:Wq 2:bq 3:Wk 4:bk 5:Wv 6:bv
    // softmax rows sum to 1 => out = X @ Wv^T + bv exactly.
    const float* X  = (const float*)d_in[0];
    const float* Wv = (const float*)d_in[5];
    const float* bv = (const float*)d_in[6];
    float* out = (float*)d_out;

    const size_t XB_BYTES = (size_t)M_TOTAL * K_TOTAL * 2;   // 32 MiB
    const size_t WB_BYTES = (size_t)N_TOTAL * K_TOTAL * 2;   // 2 MiB

    if (ws_size >= XB_BYTES + WB_BYTES) {
        unsigned short* Xb = (unsigned short*)d_ws;
        unsigned short* Wb = (unsigned short*)((char*)d_ws + XB_BYTES);
        cvt2_kernel<<<dim3((N8X + N8W) / 256), dim3(256), 0, stream>>>(
            X, Wv, (uint4*)Xb, (uint4*)Wb);
        gemm8w_kernel<<<dim3(NWG), dim3(512), 0, stream>>>(Xb, Wb, bv, out);
    } else {
        fb_gemm_bias_kernel<<<dim3(NWG), dim3(256), 0, stream>>>(X, Wv, bv, out);
    }
}

// Round 17
// 60.143 us; speedup vs baseline: 1.5832x; 1.0162x over previous
//
#include <hip/hip_runtime.h>
#include <stdint.h>

#define M_TOTAL 16384
#define N_TOTAL 1024
#define K_TOTAL 1024
#define BM 128
#define BN 128
#define BK 64
#define NTILES (K_TOTAL / BK)                 // 16
#define NWG ((M_TOTAL / BM) * (N_TOTAL / BN)) // 1024

using f32x4  = __attribute__((ext_vector_type(4))) float;
using bf16x8 = __attribute__((ext_vector_type(8))) short;
using bf16x4 = __attribute__((ext_vector_type(4))) short;

#define AS1 __attribute__((address_space(1)))
#define AS3 __attribute__((address_space(3)))
#define SB() __builtin_amdgcn_sched_barrier(0)

__device__ __forceinline__ unsigned packrne(float x, float y) {
    unsigned ux = __builtin_bit_cast(unsigned, x);
    unsigned uy = __builtin_bit_cast(unsigned, y);
    ux += 0x7fffu + ((ux >> 16) & 1u);
    uy += 0x7fffu + ((uy >> 16) & 1u);
    return (ux >> 16) | (uy & 0xffff0000u);
}

// ---------------- kernel 1: fused fp32->bf16 convert of X and Wv ------------
// 102 MB total traffic, measured 15.5 us ~= HBM ceiling.
#define N8X (M_TOTAL * K_TOTAL / 8)   // 2097152
#define N8W (N_TOTAL * K_TOTAL / 8)   // 131072
__global__ __launch_bounds__(256) void cvt2_kernel(
    const float* __restrict__ X, const float* __restrict__ W,
    uint4* __restrict__ Xb, uint4* __restrict__ Wb)
{
    const int i = blockIdx.x * 256 + threadIdx.x;
    const float* src; uint4* dst; int idx;
    if (i < N8X) { src = X; dst = Xb; idx = i; }
    else         { src = W; dst = Wb; idx = i - N8X; }
    const f32x4* p = (const f32x4*)src + (size_t)idx * 2;
    const f32x4 a = p[0], b = p[1];
    uint4 r;
    r.x = packrne(a[0], a[1]);
    r.y = packrne(a[2], a[3]);
    r.z = packrne(b[0], b[1]);
    r.w = packrne(b[2], b[3]);
    dst[idx] = r;
}

// ---------------- kernel 2: 128x128 counted-vmcnt GEMM, 2 blocks/CU ---------
// C[m][n] = sum_k Xb[m][k]*Wb[n][k] + bias[n].  bf16 inputs from ws.
// 4 waves (2M x 2N, wave-tile 64x64), BK=64, LDS 64KB dbuf -> 2 blocks/CU.
// Verified r12: 43.9us, MfmaUtil 29%, VGPR 88, 0 bank conflicts, clean
// post-timing revalidation.  86% of the m97-family structure ceiling for
// this shape; r13-r16 established the neighborhood is flat or worse.
// Per tile: B1 barrier (prev compute done reading nbuf) -> stage A,B(t+1)
// into nbuf (8 gload_lds) -> VM(8) counted (retires tile-t's 8; t+1's fly)
// -> B2 barrier -> compute tile t (2 k-half phases, 16 MFMA each, setprio).
// LDS: row r (128B) holds k-group kg at 16B slot kg^(r&7); linear gload_lds
// dest + pre-swizzled global source.
__global__ __launch_bounds__(256) void gemm2b_kernel(
    const unsigned short* __restrict__ Xb, const unsigned short* __restrict__ Wb,
    const float* __restrict__ bias, float* __restrict__ C)
{
    __shared__ __align__(16) char smem[65536]; // A0@0 A1@16384 B0@32768 B1@49152

    const int tid  = threadIdx.x;
    const int lane = tid & 63;
    const int wave = tid >> 6;      // 0..3
    const int wr = wave >> 1;       // 0..1 : 64-row strip
    const int wc = wave & 1;        // 0..1 : 64-col strip

    // XCD-chunked swizzle (verified r2-r15: X panel fetched ~once into L2)
    const int bid  = blockIdx.x;
    const int work = (bid & 7) * (NWG / 8) + (bid >> 3);
    const int bm = work >> 3;
    const int bn = work & 7;
    const int m0 = bm * BM, n0 = bn * BN;

    // staging: issue j covers 32 rows; wave w rows j*32+w*8..+8; lane l ->
    // row +(l>>3), slot l&7; source k-group (l&7)^((l>>3)&7) (pre-swizzle).
    const int srow = wave * 8 + (lane >> 3);                // row in 32-stripe
    const int kge  = ((lane & 7) ^ ((lane >> 3) & 7)) * 8;  // swizzled k elems

    auto stage = [&](int t, int b) {
        #pragma unroll
        for (int j = 0; j < 4; ++j) {   // A: 4 x 32 rows
            __builtin_amdgcn_global_load_lds(
                (const AS1 void*)(Xb + (size_t)(m0 + j * 32 + srow) * K_TOTAL
                                     + t * BK + kge),
                (AS3 void*)(smem + b * 16384 + j * 4096 + wave * 1024),
                16, 0, 0);
        }
        #pragma unroll
        for (int j = 0; j < 4; ++j) {   // B: 4 x 32 rows
            __builtin_amdgcn_global_load_lds(
                (const AS1 void*)(Wb + (size_t)(n0 + j * 32 + srow) * K_TOTAL
                                     + t * BK + kge),
                (AS3 void*)(smem + 32768 + b * 16384 + j * 4096 + wave * 1024),
                16, 0, 0);
        }
    };

    const int cl = lane & 15;
    const int kb = lane >> 4;       // 0..3

    f32x4 acc[4][4] = {};

#define BARRIER() SB(); __builtin_amdgcn_s_barrier(); SB()
#define VM(N)     asm volatile("s_waitcnt vmcnt(" #N ")" ::: "memory"); SB()

    auto compute_tile = [&](int buf) {
        const char* Ab = smem + buf * 16384;
        const char* Bb = smem + 32768 + buf * 16384;
        #pragma unroll
        for (int ks = 0; ks < 2; ++ks) {
            const int kg = ks * 4 + kb;
            bf16x8 aF[4], bF[4];
            #pragma unroll
            for (int i = 0; i < 4; ++i) {
                const int ar = wr * 64 + i * 16 + cl;
                aF[i] = *(const bf16x8*)(Ab + ar * 128 + ((kg ^ (ar & 7)) << 4));
                const int br = wc * 64 + i * 16 + cl;
                bF[i] = *(const bf16x8*)(Bb + br * 128 + ((kg ^ (br & 7)) << 4));
            }
            __builtin_amdgcn_s_setprio(1);
            #pragma unroll
            for (int i = 0; i < 4; ++i)
                #pragma unroll
                for (int j = 0; j < 4; ++j)
                    acc[i][j] = __builtin_amdgcn_mfma_f32_16x16x32_bf16(
                        aF[i], bF[j], acc[i][j], 0, 0, 0);
            __builtin_amdgcn_s_setprio(0);
        }
    };

    // ---- prologue: tiles 0 and 1 staged; tile 0 landed, tile 1 in flight ---
    stage(0, 0);
    stage(1, 1);
    VM(8);
    BARRIER();
    compute_tile(0);

    // ---- main loop ---------------------------------------------------------
    #pragma unroll 1
    for (int t = 1; t < NTILES; ++t) {
        const int buf = t & 1, nbuf = buf ^ 1;
        BARRIER();                          // B1: all waves done reading nbuf
        if (t + 1 < NTILES) {
            stage(t + 1, nbuf);
            VM(8);                          // retire tile-t's 8; t+1's fly
        } else {
            VM(0);                          // final tile: drain
        }
        BARRIER();                          // B2: tile t fully in LDS
        compute_tile(buf);
    }

    // ---- epilogue: D element (row=(lane>>4)*4+r, col=lane&15) [m89] --------
    const int r0 = (lane >> 4) * 4;
    #pragma unroll
    for (int ni = 0; ni < 4; ++ni) {
        const int n = n0 + wc * 64 + ni * 16 + cl;
        const float bvv = bias[n];
        #pragma unroll
        for (int mi = 0; mi < 4; ++mi) {
            const int m = m0 + wr * 64 + mi * 16 + r0;
            #pragma unroll
            for (int r = 0; r < 4; ++r)
                C[(size_t)(m + r) * N_TOTAL + n] = acc[mi][ni][r] + bvv;
        }
    }
#undef BARRIER
#undef VM
}

// ---------------- fallback: round-1 single kernel (known-good) --------------
__device__ __forceinline__ short f2bf(float f) {
    unsigned u = __builtin_bit_cast(unsigned, f);
    u += 0x7fffu + ((u >> 16) & 1u);
    return (short)(u >> 16);
}

__global__ __launch_bounds__(256) void fb_gemm_bias_kernel(
    const float* __restrict__ X, const float* __restrict__ W,
    const float* __restrict__ bias, float* __restrict__ C)
{
    __shared__ short As[BM * BK];
    __shared__ short Bs[BN * BK];

    const int tid  = threadIdx.x;
    const int lane = tid & 63;
    const int wave = tid >> 6;
    const int wr = wave >> 1;
    const int wc = wave & 1;

    const int bid  = blockIdx.x;
    const int work = (bid & 7) * (NWG / 8) + (bid >> 3);
    const int bm = work >> 3;
    const int bn = work & 7;
    const int m0 = bm * BM, n0 = bn * BN;

    const int srow  = tid >> 4;
    const int scol4 = tid & 15;

    f32x4 acc[4][4] = {};
    char* const Ab = (char*)As;
    char* const Bb = (char*)Bs;

    for (int k0 = 0; k0 < K_TOTAL; k0 += BK) {
        __syncthreads();
        #pragma unroll
        for (int pass = 0; pass < 8; ++pass) {
            const int row = srow + pass * 16;
            const int off = (row * (BK * 2) + scol4 * 8) ^ ((row & 7) << 4);
            {
                const f32x4 v = *(const f32x4*)(X + (size_t)(m0 + row) * K_TOTAL + k0 + scol4 * 4);
                bf16x4 b;
                b[0] = f2bf(v[0]); b[1] = f2bf(v[1]); b[2] = f2bf(v[2]); b[3] = f2bf(v[3]);
                *(bf16x4*)(Ab + off) = b;
            }
            {
                const f32x4 v = *(const f32x4*)(W + (size_t)(n0 + row) * K_TOTAL + k0 + scol4 * 4);
                bf16x4 b;
                b[0] = f2bf(v[0]); b[1] = f2bf(v[1]); b[2] = f2bf(v[2]); b[3] = f2bf(v[3]);
                *(bf16x4*)(Bb + off) = b;
            }
        }
        __syncthreads();

        #pragma unroll
        for (int ks = 0; ks < 2; ++ks) {
            const int kel = ks * 32 + ((lane >> 4) << 3);
            bf16x8 af[4], bfr[4];
            #pragma unroll
            for (int i = 0; i < 4; ++i) {
                const int ar = wr * 64 + i * 16 + (lane & 15);
                af[i]  = *(const bf16x8*)(Ab + ((ar * (BK * 2) + kel * 2) ^ ((ar & 7) << 4)));
                const int br = wc * 64 + i * 16 + (lane & 15);
                bfr[i] = *(const bf16x8*)(Bb + ((br * (BK * 2) + kel * 2) ^ ((br & 7) << 4)));
            }
            #pragma unroll
            for (int mi = 0; mi < 4; ++mi)
                #pragma unroll
                for (int ni = 0; ni < 4; ++ni)
                    acc[mi][ni] = __builtin_amdgcn_mfma_f32_16x16x32_bf16(
                        af[mi], bfr[ni], acc[mi][ni], 0, 0, 0);
        }
    }

    const int cl = lane & 15;
    const int r0 = (lane >> 4) * 4;
    #pragma unroll
    for (int ni = 0; ni < 4; ++ni) {
        const int n = n0 + wc * 64 + ni * 16 + cl;
        const float bvv = bias[n];
        #pragma unroll
        for (int mi = 0; mi < 4; ++mi) {
            const int m = m0 + wr * 64 + mi * 16 + r0;
            #pragma unroll
            for (int r = 0; r < 4; ++r)
                C[(size_t)(m + r) * N_TOTAL + n] = acc[mi][ni][r] + bvv;
        }
    }
}

extern "C" void kernel_launch(void* const* d_in, const int* in_sizes, int n_in,
                              void* d_out, int out_size, void* d_ws, size_t ws_size,
                              hipStream_t stream) {
    // inputs: 0:X 1:Wq 2:bq 3:Wk 4:bk 5:Wv 6:bv
    // softmax rows sum to 1 => out = X @ Wv^T + bv exactly.
    const float* X  = (const float*)d_in[0];
    const float* Wv = (const float*)d_in[5];
    const float* bv = (const float*)d_in[6];
    float* out = (float*)d_out;

    const size_t XB_BYTES = (size_t)M_TOTAL * K_TOTAL * 2;   // 32 MiB
    const size_t WB_BYTES = (size_t)N_TOTAL * K_TOTAL * 2;   // 2 MiB

    if (ws_size >= XB_BYTES + WB_BYTES) {
        unsigned short* Xb = (unsigned short*)d_ws;
        unsigned short* Wb = (unsigned short*)((char*)d_ws + XB_BYTES);
        cvt2_kernel<<<dim3((N8X + N8W) / 256), dim3(256), 0, stream>>>(
            X, Wv, (uint4*)Xb, (uint4*)Wb);
        gemm2b_kernel<<<dim3(NWG), dim3(256), 0, stream>>>(Xb, Wb, bv, out);
    } else {
        fb_gemm_bias_kernel<<<dim3(NWG), dim3(256), 0, stream>>>(X, Wv, bv, out);
    }
}